// Round 13
// baseline (419.431 us; speedup 1.0000x reference)
//
#include <hip/hip_runtime.h>
#include <math.h>

// Problem constants
#define NSEQ 8192          // B*N
#define PATCHL 16
#define HIDN 256
#define VOCABN 256

typedef __attribute__((ext_vector_type(4))) float f32x4;
typedef __attribute__((ext_vector_type(8))) short bf16x8;   // 8 bf16 = 4 VGPRs

__device__ __forceinline__ unsigned short f2bf(float f) {
    unsigned int x = __float_as_uint(f);
    unsigned int r = (x + 0x7fffu + ((x >> 16) & 1u)) >> 16;
    return (unsigned short)r;
}
__device__ __forceinline__ float bf2f(unsigned short b) {
    return __uint_as_float(((unsigned int)b) << 16);
}
__device__ __forceinline__ float sigf(float x)   { return 1.f / (1.f + __expf(-x)); }
__device__ __forceinline__ float tanhf_(float x) { return 2.f / (1.f + __expf(-2.f * x)) - 1.f; }

// ---------------------------------------------------------------------------
// Fragment-order bf16 pack of a weight matrix slice (MFMA B operand).
// ---------------------------------------------------------------------------
__global__ __launch_bounds__(256)
void pack_frag(const float* __restrict__ src, int ld, int col0, int nks,
               unsigned short* __restrict__ dst)
{
    const int g = blockIdx.x * 256 + threadIdx.x;
    const int lane = g & 63;
    const int ks = (g / 64) % nks;
    const int T  = g / (64 * nks);
    const float* s = src + (size_t)(T * 16 + (lane & 15)) * ld + col0 + ks * 32 + ((lane >> 4) & 3) * 8;
    unsigned int q[4];
#pragma unroll
    for (int j = 0; j < 4; j++) {
        unsigned int lo = f2bf(s[2 * j]);
        unsigned int hi = f2bf(s[2 * j + 1]);
        q[j] = lo | (hi << 16);
    }
    uint4 v; v.x = q[0]; v.y = q[1]; v.z = q[2]; v.w = q[3];
    *(uint4*)(dst + (size_t)g * 8) = v;
}

// ---------------------------------------------------------------------------
// bf16 MFMA GEMM: C[m][n] = sum_k A[m][k] * W[n][k] (+bias[n])
// BM=128 BN=64 BK=64, 512 threads (8 waves). Verified rounds 3-12.
// OUT_MODE: 0 = f32 row-major, 1 = bf16 row-major, 2 = bf16 gate4 interleave.
// ---------------------------------------------------------------------------
template<bool ASRC_BF16, int OUT_MODE>
__global__ __launch_bounds__(512)
void gemm_mfma(const void* __restrict__ Asrc, int lda,
               const unsigned short* __restrict__ bpack, int nks_total,
               const float* __restrict__ bias, void* __restrict__ Cdst, int ldc,
               int K)
{
    const int tid = threadIdx.x;
    const int w = tid >> 6, lane = tid & 63;
    const int l15 = lane & 15, kg = (lane >> 4) & 3;
    const int bm = blockIdx.x * 128, bn = blockIdx.y * 64;

    __shared__ unsigned short As[2][128 * 64];

    const int srow = tid >> 2;           // 0..127
    const int scol = (tid & 3) * 16;     // 0,16,32,48
    const int nkt = K / 64;

    f32x4 acc[4];
#pragma unroll
    for (int nt = 0; nt < 4; nt++) acc[nt] = 0.f;

    const int wb0 = srow * 128 + ((scol * 2) ^ ((srow & 7) << 4));
    const int wb1 = srow * 128 + ((scol * 2 + 16) ^ ((srow & 7) << 4));

#define STAGE(kt, buf) do {                                                         \
        const int gk = (kt) * 64 + scol;                                            \
        unsigned short tmp[16];                                                     \
        if (ASRC_BF16) {                                                            \
            const unsigned short* A = (const unsigned short*)Asrc;                  \
            *(uint4*)(tmp)     = *(const uint4*)(A + (size_t)(bm + srow) * lda + gk);      \
            *(uint4*)(tmp + 8) = *(const uint4*)(A + (size_t)(bm + srow) * lda + gk + 8);  \
        } else {                                                                    \
            const float* A = (const float*)Asrc;                                    \
            const float4 a0 = *(const float4*)(A + (size_t)(bm + srow) * lda + gk);       \
            const float4 a1 = *(const float4*)(A + (size_t)(bm + srow) * lda + gk + 4);   \
            const float4 a2 = *(const float4*)(A + (size_t)(bm + srow) * lda + gk + 8);   \
            const float4 a3 = *(const float4*)(A + (size_t)(bm + srow) * lda + gk + 12);  \
            tmp[0] = f2bf(a0.x);  tmp[1] = f2bf(a0.y);  tmp[2] = f2bf(a0.z);  tmp[3] = f2bf(a0.w);   \
            tmp[4] = f2bf(a1.x);  tmp[5] = f2bf(a1.y);  tmp[6] = f2bf(a1.z);  tmp[7] = f2bf(a1.w);   \
            tmp[8] = f2bf(a2.x);  tmp[9] = f2bf(a2.y);  tmp[10] = f2bf(a2.z); tmp[11] = f2bf(a2.w);  \
            tmp[12] = f2bf(a3.x); tmp[13] = f2bf(a3.y); tmp[14] = f2bf(a3.z); tmp[15] = f2bf(a3.w);  \
        }                                                                           \
        *(uint4*)((char*)As[buf] + wb0) = *(uint4*)tmp;                             \
        *(uint4*)((char*)As[buf] + wb1) = *(uint4*)(tmp + 8);                       \
    } while (0)

    STAGE(0, 0);
    __syncthreads();

    for (int kt = 0; kt < nkt; ++kt) {
        if (kt + 1 < nkt) STAGE(kt + 1, (kt + 1) & 1);
        const unsigned short* buf = As[kt & 1];
        const int row = w * 16 + l15;
#pragma unroll
        for (int ks = 0; ks < 2; ++ks) {
            const int bo = row * 128 + (((ks * 64) + kg * 16) ^ ((row & 7) << 4));
            const bf16x8 a = *(const bf16x8*)((const char*)buf + bo);
#pragma unroll
            for (int nt = 0; nt < 4; ++nt) {
                const int T = blockIdx.y * 4 + nt;
                const bf16x8 b = *(const bf16x8*)(bpack + (((size_t)T * nks_total + (kt * 2 + ks)) * 64 + lane) * 8);
                acc[nt] = __builtin_amdgcn_mfma_f32_16x16x32_bf16(a, b, acc[nt], 0, 0, 0);
            }
        }
        __syncthreads();
    }
#undef STAGE

#pragma unroll
    for (int nt = 0; nt < 4; ++nt) {
        const int n = bn + nt * 16 + l15;
        const float bv = bias ? bias[n] : 0.f;
#pragma unroll
        for (int rr = 0; rr < 4; ++rr) {
            const int m = bm + w * 16 + kg * 4 + rr;
            const float v = acc[nt][rr] + bv;
            if (OUT_MODE == 0)      ((float*)Cdst)[(size_t)m * ldc + n] = v;
            else if (OUT_MODE == 1) ((unsigned short*)Cdst)[(size_t)m * ldc + n] = f2bf(v);
            else                    ((unsigned short*)Cdst)[(size_t)m * 1024 + (n & 255) * 4 + (n >> 8)] = f2bf(v);
        }
    }
}

// ---------------------------------------------------------------------------
// Fused GRU scan, 32 seqs/block, 1024 threads (16 waves), 150 KB LDS,
// 1 block/CU = 16 waves/CU = 4 waves/SIMD (same wave-parallelism as r11's
// 2x8-wave blocks, but HALF the L2 weight traffic: one 384 KB wpack stream
// serves 32 seqs). Gate-specialized waves: wave w owns hidden units
// [16w,16w+16) and ONLY its 3 gate tiles {w,16+w,32+w} -> acc = 24 VGPRs
// (vs 48 in the 8-wave shape). MFMA loop: per half-K preload 8 A-frags
// (LDS, reused 3x), per gate a 4-fragment B-burst. ~108 VGPRs, fits the
// compiler's hard 128 cap with zero spill (r6-r12 lesson).
// ---------------------------------------------------------------------------
#define G4S 1032   // gate4 row stride in shorts (1024 + 8 pad)
__global__ __launch_bounds__(1024)
void gru_scan_fused(const int* __restrict__ bytes,          // [NSEQ*16]
                    const unsigned short* __restrict__ latg4,   // [NSEQ][1024] gate4 bf16 (incl b_ih)
                    const unsigned short* __restrict__ pmx4,    // [256][1024] gate4 bf16
                    const unsigned short* __restrict__ wpack,   // 48 gate tiles
                    const float* __restrict__ b_hh,         // [768]
                    unsigned short* __restrict__ hh,        // [SPC*16][256] bf16
                    int seq0)
{
    const int tid  = threadIdx.x;
    const int w    = tid >> 6;          // wave 0..15 = owned unit-block
    const int lane = tid & 63;
    const int l15  = lane & 15;
    const int kg   = (lane >> 4) & 3;
    const int s0l  = blockIdx.x * 32;            // chunk-local
    const int s0g  = seq0 + s0l;                 // global

    __shared__ unsigned short PMs[32 * G4S];     // 66 KB
    __shared__ unsigned short LG[32 * G4S];      // 66 KB
    __shared__ unsigned short H[32 * 256];       // 16 KB
    __shared__ int BYs[512];                     // 2 KB

    if (tid < 512) BYs[tid] = bytes[(size_t)s0g * PATCHL + tid];

    // latg (step-invariant) -> LDS once, coalesced uint4 loads
#pragma unroll
    for (int j = 0; j < 4; ++j) {
        const int idx = j * 1024 + tid;          // uint4 index; 128 per row
        const int row = idx >> 7, col = idx & 127;
        *(uint4*)(LG + row * G4S + col * 8) =
            *(const uint4*)(latg4 + (size_t)(s0g + row) * 1024 + col * 8);
    }

    const int u = w * 16 + l15;                  // owned unit
    const float bhr = b_hh[u], bhz = b_hh[256 + u], bhn = b_hh[512 + u];

    float hreg[2][4];                            // h for (mt, rr): seq mt*16+kg*4+rr
#pragma unroll
    for (int mt = 0; mt < 2; mt++)
#pragma unroll
        for (int rr = 0; rr < 4; rr++) hreg[mt][rr] = 0.f;

    __syncthreads();    // BYs + LG ready

    for (int p = 0; p < PATCHL; ++p) {
        // ---- 1. stage premix gate4 rows for this step's bytes (L2 -> LDS) ----
#pragma unroll
        for (int j = 0; j < 4; ++j) {
            const int idx = j * 1024 + tid;      // uint4 index; 128 per row
            const int row = idx >> 7, col = idx & 127;
            const int bv = p ? BYs[row * PATCHL + p - 1] : 0;
            *(uint4*)(PMs + row * G4S + col * 8) =
                *(const uint4*)(pmx4 + (size_t)bv * 1024 + col * 8);
        }

        // ---- 2. coalesced hh write of h(p-1) (reads H, pre-overwrite) ----
        if (p) {
#pragma unroll
            for (int rj = 0; rj < 2; ++rj) {
                const int row = w * 2 + rj;
                const int boff = (lane * 8) ^ ((row & 7) << 4);   // un-swizzle
                const ushort4 v = *(const ushort4*)((const char*)(H + row * 256) + boff);
                *(ushort4*)(hh + ((size_t)(s0l + row) * PATCHL + (p - 1)) * 256 + lane * 4) = v;
            }
        }

        // ---- 3. recurrence: wave w computes its 3 gate tiles over 2 M-tiles ----
        f32x4 accr[2], accz[2], accn[2];
#pragma unroll
        for (int mt = 0; mt < 2; mt++) { accr[mt] = 0.f; accz[mt] = 0.f; accn[mt] = 0.f; }
        if (p != 0) {
#pragma unroll
            for (int ksg = 0; ksg < 2; ++ksg) {
                // preload A-frags for this half-K (reused by all 3 gates)
                bf16x8 a[2][4];
#pragma unroll
                for (int mt = 0; mt < 2; ++mt)
#pragma unroll
                    for (int j = 0; j < 4; ++j) {
                        const int s = mt * 16 + l15;
                        const int off = ((ksg * 4 + j) * 64 + kg * 16) ^ ((s & 7) << 4);
                        a[mt][j] = *(const bf16x8*)(H + s * 256 + (off >> 1));
                    }
#pragma unroll
                for (int g = 0; g < 3; ++g) {
                    const int T = g * 16 + w;
                    bf16x8 B4[4];
#pragma unroll
                    for (int j = 0; j < 4; ++j)
                        B4[j] = *(const bf16x8*)(wpack + (((size_t)T * 8 + ksg * 4 + j) * 64 + lane) * 8);
#pragma unroll
                    for (int j = 0; j < 4; ++j)
#pragma unroll
                        for (int mt = 0; mt < 2; ++mt) {
                            if (g == 0)      accr[mt] = __builtin_amdgcn_mfma_f32_16x16x32_bf16(a[mt][j], B4[j], accr[mt], 0, 0, 0);
                            else if (g == 1) accz[mt] = __builtin_amdgcn_mfma_f32_16x16x32_bf16(a[mt][j], B4[j], accz[mt], 0, 0, 0);
                            else             accn[mt] = __builtin_amdgcn_mfma_f32_16x16x32_bf16(a[mt][j], B4[j], accn[mt], 0, 0, 0);
                        }
                }
            }
        }
        __syncthreads();   // PMs staged; all H reads (copy + MFMA) complete

        // ---- 5. gates + state update; write h(p) into H ----
#pragma unroll
        for (int mt = 0; mt < 2; mt++)
#pragma unroll
            for (int rr = 0; rr < 4; rr++) {
                const int sl = mt * 16 + kg * 4 + rr;
                const ushort4 pm4 = *(const ushort4*)(PMs + sl * G4S + u * 4);
                const ushort4 lg4 = *(const ushort4*)(LG  + sl * G4S + u * 4);
                const float xr = bf2f(lg4.x) + bf2f(pm4.x) + bhr;
                const float xz = bf2f(lg4.y) + bf2f(pm4.y) + bhz;
                const float xn = bf2f(lg4.z) + bf2f(pm4.z);
                const float r = sigf(xr + accr[mt][rr]);
                const float z = sigf(xz + accz[mt][rr]);
                const float n = tanhf_(xn + r * (accn[mt][rr] + bhn));
                const float hn_ = (1.f - z) * n + z * hreg[mt][rr];
                hreg[mt][rr] = hn_;
                const int bo = (2 * u) ^ ((sl & 7) << 4);
                H[sl * 256 + (bo >> 1)] = f2bf(hn_);
            }
        __syncthreads();   // h(p) visible
    }

    // ---- final hh write for p = 15 ----
#pragma unroll
    for (int rj = 0; rj < 2; ++rj) {
        const int row = w * 2 + rj;
        const int boff = (lane * 8) ^ ((row & 7) << 4);
        const ushort4 v = *(const ushort4*)((const char*)(H + row * 256) + boff);
        *(ushort4*)(hh + ((size_t)(s0l + row) * PATCHL + (PATCHL - 1)) * 256 + lane * 4) = v;
    }
}

// ---------------------------------------------------------------------------
extern "C" void kernel_launch(void* const* d_in, const int* in_sizes, int n_in,
                              void* d_out, int out_size, void* d_ws, size_t ws_size,
                              hipStream_t stream)
{
    const float* latents = (const float*)d_in[0];   // [8192][1024]
    const int*   tb      = (const int*)d_in[1];     // [8192*16]
    const float* W_proj  = (const float*)d_in[2];   // [256][1024]
    const float* b_proj  = (const float*)d_in[3];   // [256]
    const float* emb     = (const float*)d_in[4];   // [256][256]
    const float* W_ih    = (const float*)d_in[5];   // [768][512]
    const float* W_hh    = (const float*)d_in[6];   // [768][256]
    const float* b_ih    = (const float*)d_in[7];   // [768]
    const float* b_hh    = (const float*)d_in[8];   // [768]
    const float* W_head  = (const float*)d_in[9];   // [256][256]
    const float* b_head  = (const float*)d_in[10];  // [256]
    float* out = (float*)d_out;

    // ---- workspace layout (bytes) ----
    char* w = (char*)d_ws;
    unsigned short* latg4   = (unsigned short*)w;          w += (size_t)NSEQ * 1024 * 2;    // 16.8 MB
    unsigned short* ctxb    = (unsigned short*)w;          w += (size_t)NSEQ * HIDN * 2;    // 4.2 MB
    unsigned short* pmx4    = (unsigned short*)w;          w += 256 * 1024 * 2;             // 512 KB
    unsigned short* bpack1  = (unsigned short*)w;          w += 16 * 32 * 64 * 8 * 2;
    unsigned short* bpack2  = (unsigned short*)w;          w += 48 * 8 * 64 * 8 * 2;
    unsigned short* bpack3  = (unsigned short*)w;          w += 48 * 8 * 64 * 8 * 2;
    unsigned short* wpackG  = (unsigned short*)w;          w += 48 * 8 * 64 * 8 * 2;        // gates
    unsigned short* bpackH  = (unsigned short*)w;          w += 16 * 8 * 64 * 8 * 2;        // head
    unsigned short* hh_c    = (unsigned short*)w;
    const size_t fixed_bytes = (size_t)(w - (char*)d_ws);
    const size_t chunk_full  = (size_t)NSEQ * PATCHL * 256 * 2;          // hh = 67 MB

    int nch = 1;
    while (nch < 16 && fixed_bytes + chunk_full / nch > ws_size) nch <<= 1;
    const int SPC = NSEQ / nch;                    // seqs per chunk

    // ---- weight packs (fragment-ordered bf16) ----
    hipLaunchKernelGGL(pack_frag, dim3(128), dim3(256), 0, stream, W_proj, 1024, 0, 32, bpack1);
    hipLaunchKernelGGL(pack_frag, dim3(96),  dim3(256), 0, stream, W_ih,   512, 256, 8, bpack2);
    hipLaunchKernelGGL(pack_frag, dim3(96),  dim3(256), 0, stream, W_ih,   512, 0,   8, bpack3);
    hipLaunchKernelGGL(pack_frag, dim3(96),  dim3(256), 0, stream, W_hh,   256, 0,   8, wpackG);
    hipLaunchKernelGGL(pack_frag, dim3(32),  dim3(256), 0, stream, W_head, 256, 0,   8, bpackH);

    // pmx4(gate4 bf16) = emb @ W_ih[:,0:256]^T     [256][1024]
    hipLaunchKernelGGL((gemm_mfma<false, 2>), dim3(2, 12), dim3(512), 0, stream,
                       emb, 256, bpack3, 8, nullptr, pmx4, 1024, 256);
    // ctx(bf16) = latents @ W_proj^T + b_proj      [8192][256]
    hipLaunchKernelGGL((gemm_mfma<false, 1>), dim3(NSEQ / 128, 4), dim3(512), 0, stream,
                       latents, 1024, bpack1, 32, b_proj, ctxb, 256, 1024);
    // latg4(gate4 bf16) = ctx @ W_ih[:,256:512]^T + b_ih   [8192][1024]
    hipLaunchKernelGGL((gemm_mfma<true, 2>), dim3(NSEQ / 128, 12), dim3(512), 0, stream,
                       ctxb, 256, bpack2, 8, b_ih, latg4, 1024, 256);

    // ---- per-chunk: fused scan -> head GEMM (stream-ordered) ----
    for (int c = 0; c < nch; ++c) {
        const int seq0 = c * SPC;
        hipLaunchKernelGGL(gru_scan_fused, dim3(SPC / 32), dim3(1024), 0, stream,
                           tb, latg4, pmx4, wpackG, b_hh, hh_c, seq0);
        // logits = h_hist @ W_head^T + b_head    [SPC*16][256]
        hipLaunchKernelGGL((gemm_mfma<true, 0>), dim3(SPC * PATCHL / 128, 4), dim3(512), 0, stream,
                           hh_c, 256, bpackH, 8, b_head,
                           out + (size_t)seq0 * PATCHL * VOCABN, 256, 256);
    }
}

// Round 14
// 391.007 us; speedup vs baseline: 1.0727x; 1.0727x over previous
//
#include <hip/hip_runtime.h>
#include <math.h>

// Problem constants
#define NSEQ 8192          // B*N
#define PATCHL 16
#define HIDN 256
#define VOCABN 256

typedef __attribute__((ext_vector_type(4))) float f32x4;
typedef __attribute__((ext_vector_type(8))) short bf16x8;   // 8 bf16 = 4 VGPRs

__device__ __forceinline__ unsigned short f2bf(float f) {
    unsigned int x = __float_as_uint(f);
    unsigned int r = (x + 0x7fffu + ((x >> 16) & 1u)) >> 16;
    return (unsigned short)r;
}
__device__ __forceinline__ float bf2f(unsigned short b) {
    return __uint_as_float(((unsigned int)b) << 16);
}
__device__ __forceinline__ float sigf(float x)   { return 1.f / (1.f + __expf(-x)); }
__device__ __forceinline__ float tanhf_(float x) { return 2.f / (1.f + __expf(-2.f * x)) - 1.f; }

// ---------------------------------------------------------------------------
// Fragment-order bf16 pack of a weight matrix slice (MFMA B operand).
// ---------------------------------------------------------------------------
__global__ __launch_bounds__(256)
void pack_frag(const float* __restrict__ src, int ld, int col0, int nks,
               unsigned short* __restrict__ dst)
{
    const int g = blockIdx.x * 256 + threadIdx.x;
    const int lane = g & 63;
    const int ks = (g / 64) % nks;
    const int T  = g / (64 * nks);
    const float* s = src + (size_t)(T * 16 + (lane & 15)) * ld + col0 + ks * 32 + ((lane >> 4) & 3) * 8;
    unsigned int q[4];
#pragma unroll
    for (int j = 0; j < 4; j++) {
        unsigned int lo = f2bf(s[2 * j]);
        unsigned int hi = f2bf(s[2 * j + 1]);
        q[j] = lo | (hi << 16);
    }
    uint4 v; v.x = q[0]; v.y = q[1]; v.z = q[2]; v.w = q[3];
    *(uint4*)(dst + (size_t)g * 8) = v;
}

// ---------------------------------------------------------------------------
// bf16 MFMA GEMM: C[m][n] = sum_k A[m][k] * W[n][k] (+bias[n])
// BM=128 BN=64 BK=64, 512 threads (8 waves). Verified rounds 3-13.
// OUT_MODE: 0 = f32 row-major, 1 = bf16 row-major, 2 = bf16 gate4 interleave.
// ---------------------------------------------------------------------------
template<bool ASRC_BF16, int OUT_MODE>
__global__ __launch_bounds__(512)
void gemm_mfma(const void* __restrict__ Asrc, int lda,
               const unsigned short* __restrict__ bpack, int nks_total,
               const float* __restrict__ bias, void* __restrict__ Cdst, int ldc,
               int K)
{
    const int tid = threadIdx.x;
    const int w = tid >> 6, lane = tid & 63;
    const int l15 = lane & 15, kg = (lane >> 4) & 3;
    const int bm = blockIdx.x * 128, bn = blockIdx.y * 64;

    __shared__ unsigned short As[2][128 * 64];

    const int srow = tid >> 2;           // 0..127
    const int scol = (tid & 3) * 16;     // 0,16,32,48
    const int nkt = K / 64;

    f32x4 acc[4];
#pragma unroll
    for (int nt = 0; nt < 4; nt++) acc[nt] = 0.f;

    const int wb0 = srow * 128 + ((scol * 2) ^ ((srow & 7) << 4));
    const int wb1 = srow * 128 + ((scol * 2 + 16) ^ ((srow & 7) << 4));

#define STAGE(kt, buf) do {                                                         \
        const int gk = (kt) * 64 + scol;                                            \
        unsigned short tmp[16];                                                     \
        if (ASRC_BF16) {                                                            \
            const unsigned short* A = (const unsigned short*)Asrc;                  \
            *(uint4*)(tmp)     = *(const uint4*)(A + (size_t)(bm + srow) * lda + gk);      \
            *(uint4*)(tmp + 8) = *(const uint4*)(A + (size_t)(bm + srow) * lda + gk + 8);  \
        } else {                                                                    \
            const float* A = (const float*)Asrc;                                    \
            const float4 a0 = *(const float4*)(A + (size_t)(bm + srow) * lda + gk);       \
            const float4 a1 = *(const float4*)(A + (size_t)(bm + srow) * lda + gk + 4);   \
            const float4 a2 = *(const float4*)(A + (size_t)(bm + srow) * lda + gk + 8);   \
            const float4 a3 = *(const float4*)(A + (size_t)(bm + srow) * lda + gk + 12);  \
            tmp[0] = f2bf(a0.x);  tmp[1] = f2bf(a0.y);  tmp[2] = f2bf(a0.z);  tmp[3] = f2bf(a0.w);   \
            tmp[4] = f2bf(a1.x);  tmp[5] = f2bf(a1.y);  tmp[6] = f2bf(a1.z);  tmp[7] = f2bf(a1.w);   \
            tmp[8] = f2bf(a2.x);  tmp[9] = f2bf(a2.y);  tmp[10] = f2bf(a2.z); tmp[11] = f2bf(a2.w);  \
            tmp[12] = f2bf(a3.x); tmp[13] = f2bf(a3.y); tmp[14] = f2bf(a3.z); tmp[15] = f2bf(a3.w);  \
        }                                                                           \
        *(uint4*)((char*)As[buf] + wb0) = *(uint4*)tmp;                             \
        *(uint4*)((char*)As[buf] + wb1) = *(uint4*)(tmp + 8);                       \
    } while (0)

    STAGE(0, 0);
    __syncthreads();

    for (int kt = 0; kt < nkt; ++kt) {
        if (kt + 1 < nkt) STAGE(kt + 1, (kt + 1) & 1);
        const unsigned short* buf = As[kt & 1];
        const int row = w * 16 + l15;
#pragma unroll
        for (int ks = 0; ks < 2; ++ks) {
            const int bo = row * 128 + (((ks * 64) + kg * 16) ^ ((row & 7) << 4));
            const bf16x8 a = *(const bf16x8*)((const char*)buf + bo);
#pragma unroll
            for (int nt = 0; nt < 4; ++nt) {
                const int T = blockIdx.y * 4 + nt;
                const bf16x8 b = *(const bf16x8*)(bpack + (((size_t)T * nks_total + (kt * 2 + ks)) * 64 + lane) * 8);
                acc[nt] = __builtin_amdgcn_mfma_f32_16x16x32_bf16(a, b, acc[nt], 0, 0, 0);
            }
        }
        __syncthreads();
    }
#undef STAGE

#pragma unroll
    for (int nt = 0; nt < 4; ++nt) {
        const int n = bn + nt * 16 + l15;
        const float bv = bias ? bias[n] : 0.f;
#pragma unroll
        for (int rr = 0; rr < 4; ++rr) {
            const int m = bm + w * 16 + kg * 4 + rr;
            const float v = acc[nt][rr] + bv;
            if (OUT_MODE == 0)      ((float*)Cdst)[(size_t)m * ldc + n] = v;
            else if (OUT_MODE == 1) ((unsigned short*)Cdst)[(size_t)m * ldc + n] = f2bf(v);
            else                    ((unsigned short*)Cdst)[(size_t)m * 1024 + (n & 255) * 4 + (n >> 8)] = f2bf(v);
        }
    }
}

// ---------------------------------------------------------------------------
// Fused GRU scan, 16 seqs/block, 512 threads, 42 KB LDS.
// r11 ran the same structure at 75 KB LDS and Occupancy showed only ~7
// waves/CU (1 block/CU resident) -> latency-starved at 2 waves/SIMD.
// This round drops the LG buffer (-33 KB): latg4 is read per step straight
// from L2 (8 coalesced 8-B loads/thread issued at step top, consumed at
// step end -> whole MFMA phase covers the latency; the block's 32 KB latg
// slice stays L2-hot). 42 KB -> 3 blocks/CU even if the usable pool is
// 128 KB => 24 waves/CU to hide the 384 KB/step wpackG L2 stream.
// VGPR cap is hard at 128 (= 131072 / (2 * 512)); payload ~115.
// ---------------------------------------------------------------------------
#define G4S 1032   // gate4 row stride in shorts (1024 + 8 pad)
__global__ __launch_bounds__(512)
void gru_scan_fused(const int* __restrict__ bytes,          // [NSEQ*16]
                    const unsigned short* __restrict__ latg4,   // [NSEQ][1024] gate4 bf16 (incl b_ih)
                    const unsigned short* __restrict__ pmx4,    // [256][1024] gate4 bf16
                    const unsigned short* __restrict__ wpack,   // 48 gate tiles
                    const float* __restrict__ b_hh,         // [768]
                    unsigned short* __restrict__ hh,        // [SPC*16][256] bf16
                    int seq0)
{
    const int tid  = threadIdx.x;
    const int w    = tid >> 6;
    const int lane = tid & 63;
    const int l15  = lane & 15;
    const int kg   = (lane >> 4) & 3;
    const int s0l  = blockIdx.x * 16;            // chunk-local
    const int s0g  = seq0 + s0l;                 // global

    __shared__ unsigned short PMs[16 * G4S];     // 33 KB
    __shared__ unsigned short H[16 * 256];       // 8 KB
    __shared__ int BYs[256];                     // 1 KB

    if (tid < 256) BYs[tid] = bytes[(size_t)s0g * PATCHL + tid];

    float bhr[2], bhz[2], bhn[2];
#pragma unroll
    for (int nt = 0; nt < 2; nt++) {
        const int u = w * 32 + nt * 16 + l15;
        bhr[nt] = b_hh[u]; bhz[nt] = b_hh[256 + u]; bhn[nt] = b_hh[512 + u];
    }

    float hreg[2][4];
#pragma unroll
    for (int nt = 0; nt < 2; nt++)
#pragma unroll
        for (int rr = 0; rr < 4; rr++) hreg[nt][rr] = 0.f;

    __syncthreads();    // BYs ready

    for (int p = 0; p < PATCHL; ++p) {
        // ---- 0. issue this step's latg reads (consumed in gate phase) ----
        ushort4 lg4[2][4];
#pragma unroll
        for (int nt = 0; nt < 2; nt++) {
            const int u = w * 32 + nt * 16 + l15;
#pragma unroll
            for (int rr = 0; rr < 4; rr++) {
                const int sl = kg * 4 + rr;
                lg4[nt][rr] = *(const ushort4*)(latg4 + (size_t)(s0g + sl) * 1024 + u * 4);
            }
        }

        // ---- 1. stage premix gate4 rows for this step's bytes (L2 -> LDS) ----
#pragma unroll
        for (int j = 0; j < 4; ++j) {
            const int idx = j * 512 + tid;       // uint4 index; 128 per row
            const int row = idx >> 7, col = idx & 127;
            const int bv = p ? BYs[row * PATCHL + p - 1] : 0;
            *(uint4*)(PMs + row * G4S + col * 8) =
                *(const uint4*)(pmx4 + (size_t)bv * 1024 + col * 8);
        }

        // ---- 2. coalesced hh write of h(p-1) (reads H, pre-overwrite) ----
        if (p) {
#pragma unroll
            for (int rj = 0; rj < 2; ++rj) {
                const int row = w * 2 + rj;
                const int boff = (lane * 8) ^ ((row & 7) << 4);   // un-swizzle
                const ushort4 v = *(const ushort4*)((const char*)(H + row * 256) + boff);
                *(ushort4*)(hh + ((size_t)(s0l + row) * PATCHL + (p - 1)) * 256 + lane * 4) = v;
            }
        }

        // ---- 3. recurrence: hg = h(p-1) @ W_hh^T (one M-tile) ----
        f32x4 accr[2], accz[2], accn[2];
#pragma unroll
        for (int nt = 0; nt < 2; nt++) { accr[nt] = 0.f; accz[nt] = 0.f; accn[nt] = 0.f; }
        if (p != 0) {
#pragma unroll
            for (int ks = 0; ks < 8; ++ks) {
                const int s = l15;
                const int off = (ks * 64 + kg * 16) ^ ((s & 7) << 4);
                const bf16x8 a = *(const bf16x8*)(H + s * 256 + (off >> 1));
#pragma unroll
                for (int nt = 0; nt < 2; nt++) {
                    const int tb = w * 2 + nt;
                    const bf16x8 br = *(const bf16x8*)(wpack + (((size_t)(tb)      * 8 + ks) * 64 + lane) * 8);
                    const bf16x8 bz = *(const bf16x8*)(wpack + (((size_t)(16 + tb) * 8 + ks) * 64 + lane) * 8);
                    const bf16x8 bn = *(const bf16x8*)(wpack + (((size_t)(32 + tb) * 8 + ks) * 64 + lane) * 8);
                    accr[nt] = __builtin_amdgcn_mfma_f32_16x16x32_bf16(a, br, accr[nt], 0, 0, 0);
                    accz[nt] = __builtin_amdgcn_mfma_f32_16x16x32_bf16(a, bz, accz[nt], 0, 0, 0);
                    accn[nt] = __builtin_amdgcn_mfma_f32_16x16x32_bf16(a, bn, accn[nt], 0, 0, 0);
                }
            }
        }
        __syncthreads();   // PMs staged; all H reads (copy + MFMA) complete

        // ---- 5. gates + state update; write h(p) into H ----
#pragma unroll
        for (int nt = 0; nt < 2; nt++) {
            const int u = w * 32 + nt * 16 + l15;
#pragma unroll
            for (int rr = 0; rr < 4; rr++) {
                const int sl = kg * 4 + rr;
                const ushort4 pm4 = *(const ushort4*)(PMs + sl * G4S + u * 4);
                const float xr = bf2f(lg4[nt][rr].x) + bf2f(pm4.x) + bhr[nt];
                const float xz = bf2f(lg4[nt][rr].y) + bf2f(pm4.y) + bhz[nt];
                const float xn = bf2f(lg4[nt][rr].z) + bf2f(pm4.z);
                const float r = sigf(xr + accr[nt][rr]);
                const float z = sigf(xz + accz[nt][rr]);
                const float n = tanhf_(xn + r * (accn[nt][rr] + bhn[nt]));
                const float hn_ = (1.f - z) * n + z * hreg[nt][rr];
                hreg[nt][rr] = hn_;
                const int bo = (2 * u) ^ ((sl & 7) << 4);
                H[sl * 256 + (bo >> 1)] = f2bf(hn_);
            }
        }
        __syncthreads();   // h(p) visible
    }

    // ---- final hh write for p = 15 ----
#pragma unroll
    for (int rj = 0; rj < 2; ++rj) {
        const int row = w * 2 + rj;
        const int boff = (lane * 8) ^ ((row & 7) << 4);
        const ushort4 v = *(const ushort4*)((const char*)(H + row * 256) + boff);
        *(ushort4*)(hh + ((size_t)(s0l + row) * PATCHL + (PATCHL - 1)) * 256 + lane * 4) = v;
    }
}

// ---------------------------------------------------------------------------
extern "C" void kernel_launch(void* const* d_in, const int* in_sizes, int n_in,
                              void* d_out, int out_size, void* d_ws, size_t ws_size,
                              hipStream_t stream)
{
    const float* latents = (const float*)d_in[0];   // [8192][1024]
    const int*   tb      = (const int*)d_in[1];     // [8192*16]
    const float* W_proj  = (const float*)d_in[2];   // [256][1024]
    const float* b_proj  = (const float*)d_in[3];   // [256]
    const float* emb     = (const float*)d_in[4];   // [256][256]
    const float* W_ih    = (const float*)d_in[5];   // [768][512]
    const float* W_hh    = (const float*)d_in[6];   // [768][256]
    const float* b_ih    = (const float*)d_in[7];   // [768]
    const float* b_hh    = (const float*)d_in[8];   // [768]
    const float* W_head  = (const float*)d_in[9];   // [256][256]
    const float* b_head  = (const float*)d_in[10];  // [256]
    float* out = (float*)d_out;

    // ---- workspace layout (bytes) ----
    char* w = (char*)d_ws;
    unsigned short* latg4   = (unsigned short*)w;          w += (size_t)NSEQ * 1024 * 2;    // 16.8 MB
    unsigned short* ctxb    = (unsigned short*)w;          w += (size_t)NSEQ * HIDN * 2;    // 4.2 MB
    unsigned short* pmx4    = (unsigned short*)w;          w += 256 * 1024 * 2;             // 512 KB
    unsigned short* bpack1  = (unsigned short*)w;          w += 16 * 32 * 64 * 8 * 2;
    unsigned short* bpack2  = (unsigned short*)w;          w += 48 * 8 * 64 * 8 * 2;
    unsigned short* bpack3  = (unsigned short*)w;          w += 48 * 8 * 64 * 8 * 2;
    unsigned short* wpackG  = (unsigned short*)w;          w += 48 * 8 * 64 * 8 * 2;        // gates
    unsigned short* bpackH  = (unsigned short*)w;          w += 16 * 8 * 64 * 8 * 2;        // head
    unsigned short* hh_c    = (unsigned short*)w;
    const size_t fixed_bytes = (size_t)(w - (char*)d_ws);
    const size_t chunk_full  = (size_t)NSEQ * PATCHL * 256 * 2;          // hh = 67 MB

    int nch = 1;
    while (nch < 16 && fixed_bytes + chunk_full / nch > ws_size) nch <<= 1;
    const int SPC = NSEQ / nch;                    // seqs per chunk

    // ---- weight packs (fragment-ordered bf16) ----
    hipLaunchKernelGGL(pack_frag, dim3(128), dim3(256), 0, stream, W_proj, 1024, 0, 32, bpack1);
    hipLaunchKernelGGL(pack_frag, dim3(96),  dim3(256), 0, stream, W_ih,   512, 256, 8, bpack2);
    hipLaunchKernelGGL(pack_frag, dim3(96),  dim3(256), 0, stream, W_ih,   512, 0,   8, bpack3);
    hipLaunchKernelGGL(pack_frag, dim3(96),  dim3(256), 0, stream, W_hh,   256, 0,   8, wpackG);
    hipLaunchKernelGGL(pack_frag, dim3(32),  dim3(256), 0, stream, W_head, 256, 0,   8, bpackH);

    // pmx4(gate4 bf16) = emb @ W_ih[:,0:256]^T     [256][1024]
    hipLaunchKernelGGL((gemm_mfma<false, 2>), dim3(2, 12), dim3(512), 0, stream,
                       emb, 256, bpack3, 8, nullptr, pmx4, 1024, 256);
    // ctx(bf16) = latents @ W_proj^T + b_proj      [8192][256]
    hipLaunchKernelGGL((gemm_mfma<false, 1>), dim3(NSEQ / 128, 4), dim3(512), 0, stream,
                       latents, 1024, bpack1, 32, b_proj, ctxb, 256, 1024);
    // latg4(gate4 bf16) = ctx @ W_ih[:,256:512]^T + b_ih   [8192][1024]
    hipLaunchKernelGGL((gemm_mfma<true, 2>), dim3(NSEQ / 128, 12), dim3(512), 0, stream,
                       ctxb, 256, bpack2, 8, b_ih, latg4, 1024, 256);

    // ---- per-chunk: fused scan -> head GEMM (stream-ordered) ----
    for (int c = 0; c < nch; ++c) {
        const int seq0 = c * SPC;
        hipLaunchKernelGGL(gru_scan_fused, dim3(SPC / 16), dim3(512), 0, stream,
                           tb, latg4, pmx4, wpackG, b_hh, hh_c, seq0);
        // logits = h_hist @ W_head^T + b_head    [SPC*16][256]
        hipLaunchKernelGGL((gemm_mfma<true, 0>), dim3(SPC * PATCHL / 128, 4), dim3(512), 0, stream,
                           hh_c, 256, bpackH, 8, b_head,
                           out + (size_t)seq0 * PATCHL * VOCABN, 256, 256);
    }
}

// Round 15
// 353.429 us; speedup vs baseline: 1.1867x; 1.1063x over previous
//
#include <hip/hip_runtime.h>
#include <math.h>

// Problem constants
#define NSEQ 8192          // B*N
#define PATCHL 16
#define HIDN 256
#define VOCABN 256

typedef __attribute__((ext_vector_type(4))) float f32x4;
typedef __attribute__((ext_vector_type(8))) short bf16x8;   // 8 bf16 = 4 VGPRs

__device__ __forceinline__ unsigned short f2bf(float f) {
    unsigned int x = __float_as_uint(f);
    unsigned int r = (x + 0x7fffu + ((x >> 16) & 1u)) >> 16;
    return (unsigned short)r;
}
__device__ __forceinline__ float bf2f(unsigned short b) {
    return __uint_as_float(((unsigned int)b) << 16);
}
__device__ __forceinline__ float sigf(float x)   { return 1.f / (1.f + __expf(-x)); }
__device__ __forceinline__ float tanhf_(float x) { return 2.f / (1.f + __expf(-2.f * x)) - 1.f; }

// ---------------------------------------------------------------------------
// Fragment-order bf16 pack of a weight matrix slice (MFMA B operand).
// ---------------------------------------------------------------------------
__global__ __launch_bounds__(256)
void pack_frag(const float* __restrict__ src, int ld, int col0, int nks,
               unsigned short* __restrict__ dst)
{
    const int g = blockIdx.x * 256 + threadIdx.x;
    const int lane = g & 63;
    const int ks = (g / 64) % nks;
    const int T  = g / (64 * nks);
    const float* s = src + (size_t)(T * 16 + (lane & 15)) * ld + col0 + ks * 32 + ((lane >> 4) & 3) * 8;
    unsigned int q[4];
#pragma unroll
    for (int j = 0; j < 4; j++) {
        unsigned int lo = f2bf(s[2 * j]);
        unsigned int hi = f2bf(s[2 * j + 1]);
        q[j] = lo | (hi << 16);
    }
    uint4 v; v.x = q[0]; v.y = q[1]; v.z = q[2]; v.w = q[3];
    *(uint4*)(dst + (size_t)g * 8) = v;
}

// ---------------------------------------------------------------------------
// bf16 MFMA GEMM: C[m][n] = sum_k A[m][k] * W[n][k] (+bias[n])
// BM=128 BN=64 BK=64, 512 threads (8 waves). Verified rounds 3-14.
// OUT_MODE: 0 = f32 row-major, 1 = bf16 row-major, 2 = bf16 gate4 interleave.
// ---------------------------------------------------------------------------
template<bool ASRC_BF16, int OUT_MODE>
__global__ __launch_bounds__(512)
void gemm_mfma(const void* __restrict__ Asrc, int lda,
               const unsigned short* __restrict__ bpack, int nks_total,
               const float* __restrict__ bias, void* __restrict__ Cdst, int ldc,
               int K)
{
    const int tid = threadIdx.x;
    const int w = tid >> 6, lane = tid & 63;
    const int l15 = lane & 15, kg = (lane >> 4) & 3;
    const int bm = blockIdx.x * 128, bn = blockIdx.y * 64;

    __shared__ unsigned short As[2][128 * 64];

    const int srow = tid >> 2;           // 0..127
    const int scol = (tid & 3) * 16;     // 0,16,32,48
    const int nkt = K / 64;

    f32x4 acc[4];
#pragma unroll
    for (int nt = 0; nt < 4; nt++) acc[nt] = 0.f;

    const int wb0 = srow * 128 + ((scol * 2) ^ ((srow & 7) << 4));
    const int wb1 = srow * 128 + ((scol * 2 + 16) ^ ((srow & 7) << 4));

#define STAGE(kt, buf) do {                                                         \
        const int gk = (kt) * 64 + scol;                                            \
        unsigned short tmp[16];                                                     \
        if (ASRC_BF16) {                                                            \
            const unsigned short* A = (const unsigned short*)Asrc;                  \
            *(uint4*)(tmp)     = *(const uint4*)(A + (size_t)(bm + srow) * lda + gk);      \
            *(uint4*)(tmp + 8) = *(const uint4*)(A + (size_t)(bm + srow) * lda + gk + 8);  \
        } else {                                                                    \
            const float* A = (const float*)Asrc;                                    \
            const float4 a0 = *(const float4*)(A + (size_t)(bm + srow) * lda + gk);       \
            const float4 a1 = *(const float4*)(A + (size_t)(bm + srow) * lda + gk + 4);   \
            const float4 a2 = *(const float4*)(A + (size_t)(bm + srow) * lda + gk + 8);   \
            const float4 a3 = *(const float4*)(A + (size_t)(bm + srow) * lda + gk + 12);  \
            tmp[0] = f2bf(a0.x);  tmp[1] = f2bf(a0.y);  tmp[2] = f2bf(a0.z);  tmp[3] = f2bf(a0.w);   \
            tmp[4] = f2bf(a1.x);  tmp[5] = f2bf(a1.y);  tmp[6] = f2bf(a1.z);  tmp[7] = f2bf(a1.w);   \
            tmp[8] = f2bf(a2.x);  tmp[9] = f2bf(a2.y);  tmp[10] = f2bf(a2.z); tmp[11] = f2bf(a2.w);  \
            tmp[12] = f2bf(a3.x); tmp[13] = f2bf(a3.y); tmp[14] = f2bf(a3.z); tmp[15] = f2bf(a3.w);  \
        }                                                                           \
        *(uint4*)((char*)As[buf] + wb0) = *(uint4*)tmp;                             \
        *(uint4*)((char*)As[buf] + wb1) = *(uint4*)(tmp + 8);                       \
    } while (0)

    STAGE(0, 0);
    __syncthreads();

    for (int kt = 0; kt < nkt; ++kt) {
        if (kt + 1 < nkt) STAGE(kt + 1, (kt + 1) & 1);
        const unsigned short* buf = As[kt & 1];
        const int row = w * 16 + l15;
#pragma unroll
        for (int ks = 0; ks < 2; ++ks) {
            const int bo = row * 128 + (((ks * 64) + kg * 16) ^ ((row & 7) << 4));
            const bf16x8 a = *(const bf16x8*)((const char*)buf + bo);
#pragma unroll
            for (int nt = 0; nt < 4; ++nt) {
                const int T = blockIdx.y * 4 + nt;
                const bf16x8 b = *(const bf16x8*)(bpack + (((size_t)T * nks_total + (kt * 2 + ks)) * 64 + lane) * 8);
                acc[nt] = __builtin_amdgcn_mfma_f32_16x16x32_bf16(a, b, acc[nt], 0, 0, 0);
            }
        }
        __syncthreads();
    }
#undef STAGE

#pragma unroll
    for (int nt = 0; nt < 4; ++nt) {
        const int n = bn + nt * 16 + l15;
        const float bv = bias ? bias[n] : 0.f;
#pragma unroll
        for (int rr = 0; rr < 4; ++rr) {
            const int m = bm + w * 16 + kg * 4 + rr;
            const float v = acc[nt][rr] + bv;
            if (OUT_MODE == 0)      ((float*)Cdst)[(size_t)m * ldc + n] = v;
            else if (OUT_MODE == 1) ((unsigned short*)Cdst)[(size_t)m * ldc + n] = f2bf(v);
            else                    ((unsigned short*)Cdst)[(size_t)m * 1024 + (n & 255) * 4 + (n >> 8)] = f2bf(v);
        }
    }
}

// ---------------------------------------------------------------------------
// Fused GRU scan = r11 structure exactly (best verified: 193 us) with ONE
// change: all 6 B-fragment loads per ks are hoisted ahead of the 6 MFMAs.
// r11 issued 3 loads -> 3 dependent MFMAs (MLP=3); at the fixed 2 waves/SIMD
// residency (AGPR+arch > 256 regs/lane-slot -> always 1 block/CU), each
// ks-group exposed a ~250cyc L2 round-trip. MLP=6 halves exposed latency.
// 16 seqs/block, 512 threads, 75 KB LDS.
// ---------------------------------------------------------------------------
#define G4S 1032   // gate4 row stride in shorts (1024 + 8 pad)
__global__ __launch_bounds__(512)
void gru_scan_fused(const int* __restrict__ bytes,          // [NSEQ*16]
                    const unsigned short* __restrict__ latg4,   // [NSEQ][1024] gate4 bf16 (incl b_ih)
                    const unsigned short* __restrict__ pmx4,    // [256][1024] gate4 bf16
                    const unsigned short* __restrict__ wpack,   // 48 gate tiles
                    const float* __restrict__ b_hh,         // [768]
                    unsigned short* __restrict__ hh,        // [SPC*16][256] bf16
                    int seq0)
{
    const int tid  = threadIdx.x;
    const int w    = tid >> 6;
    const int lane = tid & 63;
    const int l15  = lane & 15;
    const int kg   = (lane >> 4) & 3;
    const int s0l  = blockIdx.x * 16;            // chunk-local
    const int s0g  = seq0 + s0l;                 // global

    __shared__ unsigned short PMs[16 * G4S];     // 33 KB
    __shared__ unsigned short LG[16 * G4S];      // 33 KB
    __shared__ unsigned short H[16 * 256];       // 8 KB
    __shared__ int BYs[256];                     // 1 KB

    if (tid < 256) BYs[tid] = bytes[(size_t)s0g * PATCHL + tid];

    // latg (step-invariant) -> LDS once, coalesced uint4 loads
#pragma unroll
    for (int j = 0; j < 4; ++j) {
        const int idx = j * 512 + tid;           // uint4 index; 128 per row
        const int row = idx >> 7, col = idx & 127;
        *(uint4*)(LG + row * G4S + col * 8) =
            *(const uint4*)(latg4 + (size_t)(s0g + row) * 1024 + col * 8);
    }

    float bhr[2], bhz[2], bhn[2];
#pragma unroll
    for (int nt = 0; nt < 2; nt++) {
        const int u = w * 32 + nt * 16 + l15;
        bhr[nt] = b_hh[u]; bhz[nt] = b_hh[256 + u]; bhn[nt] = b_hh[512 + u];
    }

    float hreg[2][4];
#pragma unroll
    for (int nt = 0; nt < 2; nt++)
#pragma unroll
        for (int rr = 0; rr < 4; rr++) hreg[nt][rr] = 0.f;

    __syncthreads();    // BYs + LG ready

    for (int p = 0; p < PATCHL; ++p) {
        // ---- 1. stage premix gate4 rows for this step's bytes (L2 -> LDS) ----
#pragma unroll
        for (int j = 0; j < 4; ++j) {
            const int idx = j * 512 + tid;       // uint4 index; 128 per row
            const int row = idx >> 7, col = idx & 127;
            const int bv = p ? BYs[row * PATCHL + p - 1] : 0;
            *(uint4*)(PMs + row * G4S + col * 8) =
                *(const uint4*)(pmx4 + (size_t)bv * 1024 + col * 8);
        }

        // ---- 2. coalesced hh write of h(p-1) (reads H, pre-overwrite) ----
        if (p) {
#pragma unroll
            for (int rj = 0; rj < 2; ++rj) {
                const int row = w * 2 + rj;
                const int boff = (lane * 8) ^ ((row & 7) << 4);   // un-swizzle
                const ushort4 v = *(const ushort4*)((const char*)(H + row * 256) + boff);
                *(ushort4*)(hh + ((size_t)(s0l + row) * PATCHL + (p - 1)) * 256 + lane * 4) = v;
            }
        }

        // ---- 3. recurrence: hg = h(p-1) @ W_hh^T, 6 B-loads hoisted per ks ----
        f32x4 accr[2], accz[2], accn[2];
#pragma unroll
        for (int nt = 0; nt < 2; nt++) { accr[nt] = 0.f; accz[nt] = 0.f; accn[nt] = 0.f; }
        if (p != 0) {
#pragma unroll
            for (int ks = 0; ks < 8; ++ks) {
                const int off = (ks * 64 + kg * 16) ^ ((l15 & 7) << 4);
                const bf16x8 a = *(const bf16x8*)(H + l15 * 256 + (off >> 1));
                // issue all 6 independent B-fragment loads (MLP = 6)
                bf16x8 B6[6];
#pragma unroll
                for (int g = 0; g < 3; ++g)
#pragma unroll
                    for (int nt = 0; nt < 2; ++nt) {
                        const int T = g * 16 + w * 2 + nt;
                        B6[g * 2 + nt] = *(const bf16x8*)(wpack + (((size_t)T * 8 + ks) * 64 + lane) * 8);
                    }
#pragma unroll
                for (int nt = 0; nt < 2; ++nt) {
                    accr[nt] = __builtin_amdgcn_mfma_f32_16x16x32_bf16(a, B6[nt],     accr[nt], 0, 0, 0);
                    accz[nt] = __builtin_amdgcn_mfma_f32_16x16x32_bf16(a, B6[2 + nt], accz[nt], 0, 0, 0);
                    accn[nt] = __builtin_amdgcn_mfma_f32_16x16x32_bf16(a, B6[4 + nt], accn[nt], 0, 0, 0);
                }
            }
        }
        __syncthreads();   // PMs staged; all H reads (copy + MFMA) complete

        // ---- 5. gates + state update; write h(p) into H ----
#pragma unroll
        for (int nt = 0; nt < 2; nt++) {
            const int u = w * 32 + nt * 16 + l15;
#pragma unroll
            for (int rr = 0; rr < 4; rr++) {
                const int sl = kg * 4 + rr;
                const ushort4 pm4 = *(const ushort4*)(PMs + sl * G4S + u * 4);
                const ushort4 lg4 = *(const ushort4*)(LG  + sl * G4S + u * 4);
                const float xr = bf2f(lg4.x) + bf2f(pm4.x) + bhr[nt];
                const float xz = bf2f(lg4.y) + bf2f(pm4.y) + bhz[nt];
                const float xn = bf2f(lg4.z) + bf2f(pm4.z);
                const float r = sigf(xr + accr[nt][rr]);
                const float z = sigf(xz + accz[nt][rr]);
                const float n = tanhf_(xn + r * (accn[nt][rr] + bhn[nt]));
                const float hn_ = (1.f - z) * n + z * hreg[nt][rr];
                hreg[nt][rr] = hn_;
                const int bo = (2 * u) ^ ((sl & 7) << 4);
                H[sl * 256 + (bo >> 1)] = f2bf(hn_);
            }
        }
        __syncthreads();   // h(p) visible
    }

    // ---- final hh write for p = 15 ----
#pragma unroll
    for (int rj = 0; rj < 2; ++rj) {
        const int row = w * 2 + rj;
        const int boff = (lane * 8) ^ ((row & 7) << 4);
        const ushort4 v = *(const ushort4*)((const char*)(H + row * 256) + boff);
        *(ushort4*)(hh + ((size_t)(s0l + row) * PATCHL + (PATCHL - 1)) * 256 + lane * 4) = v;
    }
}

// ---------------------------------------------------------------------------
extern "C" void kernel_launch(void* const* d_in, const int* in_sizes, int n_in,
                              void* d_out, int out_size, void* d_ws, size_t ws_size,
                              hipStream_t stream)
{
    const float* latents = (const float*)d_in[0];   // [8192][1024]
    const int*   tb      = (const int*)d_in[1];     // [8192*16]
    const float* W_proj  = (const float*)d_in[2];   // [256][1024]
    const float* b_proj  = (const float*)d_in[3];   // [256]
    const float* emb     = (const float*)d_in[4];   // [256][256]
    const float* W_ih    = (const float*)d_in[5];   // [768][512]
    const float* W_hh    = (const float*)d_in[6];   // [768][256]
    const float* b_ih    = (const float*)d_in[7];   // [768]
    const float* b_hh    = (const float*)d_in[8];   // [768]
    const float* W_head  = (const float*)d_in[9];   // [256][256]
    const float* b_head  = (const float*)d_in[10];  // [256]
    float* out = (float*)d_out;

    // ---- workspace layout (bytes) ----
    char* w = (char*)d_ws;
    unsigned short* latg4   = (unsigned short*)w;          w += (size_t)NSEQ * 1024 * 2;    // 16.8 MB
    unsigned short* ctxb    = (unsigned short*)w;          w += (size_t)NSEQ * HIDN * 2;    // 4.2 MB
    unsigned short* pmx4    = (unsigned short*)w;          w += 256 * 1024 * 2;             // 512 KB
    unsigned short* bpack1  = (unsigned short*)w;          w += 16 * 32 * 64 * 8 * 2;
    unsigned short* bpack2  = (unsigned short*)w;          w += 48 * 8 * 64 * 8 * 2;
    unsigned short* bpack3  = (unsigned short*)w;          w += 48 * 8 * 64 * 8 * 2;
    unsigned short* wpackG  = (unsigned short*)w;          w += 48 * 8 * 64 * 8 * 2;        // gates
    unsigned short* bpackH  = (unsigned short*)w;          w += 16 * 8 * 64 * 8 * 2;        // head
    unsigned short* hh_c    = (unsigned short*)w;
    const size_t fixed_bytes = (size_t)(w - (char*)d_ws);
    const size_t chunk_full  = (size_t)NSEQ * PATCHL * 256 * 2;          // hh = 67 MB

    int nch = 1;
    while (nch < 16 && fixed_bytes + chunk_full / nch > ws_size) nch <<= 1;
    const int SPC = NSEQ / nch;                    // seqs per chunk

    // ---- weight packs (fragment-ordered bf16) ----
    hipLaunchKernelGGL(pack_frag, dim3(128), dim3(256), 0, stream, W_proj, 1024, 0, 32, bpack1);
    hipLaunchKernelGGL(pack_frag, dim3(96),  dim3(256), 0, stream, W_ih,   512, 256, 8, bpack2);
    hipLaunchKernelGGL(pack_frag, dim3(96),  dim3(256), 0, stream, W_ih,   512, 0,   8, bpack3);
    hipLaunchKernelGGL(pack_frag, dim3(96),  dim3(256), 0, stream, W_hh,   256, 0,   8, wpackG);
    hipLaunchKernelGGL(pack_frag, dim3(32),  dim3(256), 0, stream, W_head, 256, 0,   8, bpackH);

    // pmx4(gate4 bf16) = emb @ W_ih[:,0:256]^T     [256][1024]
    hipLaunchKernelGGL((gemm_mfma<false, 2>), dim3(2, 12), dim3(512), 0, stream,
                       emb, 256, bpack3, 8, nullptr, pmx4, 1024, 256);
    // ctx(bf16) = latents @ W_proj^T + b_proj      [8192][256]
    hipLaunchKernelGGL((gemm_mfma<false, 1>), dim3(NSEQ / 128, 4), dim3(512), 0, stream,
                       latents, 1024, bpack1, 32, b_proj, ctxb, 256, 1024);
    // latg4(gate4 bf16) = ctx @ W_ih[:,256:512]^T + b_ih   [8192][1024]
    hipLaunchKernelGGL((gemm_mfma<true, 2>), dim3(NSEQ / 128, 12), dim3(512), 0, stream,
                       ctxb, 256, bpack2, 8, b_ih, latg4, 1024, 256);

    // ---- per-chunk: fused scan -> head GEMM (stream-ordered) ----
    for (int c = 0; c < nch; ++c) {
        const int seq0 = c * SPC;
        hipLaunchKernelGGL(gru_scan_fused, dim3(SPC / 16), dim3(512), 0, stream,
                           tb, latg4, pmx4, wpackG, b_hh, hh_c, seq0);
        // logits = h_hist @ W_head^T + b_head    [SPC*16][256]
        hipLaunchKernelGGL((gemm_mfma<true, 0>), dim3(SPC * PATCHL / 128, 4), dim3(512), 0, stream,
                           hh_c, 256, bpackH, 8, b_head,
                           out + (size_t)seq0 * PATCHL * VOCABN, 256, 256);
    }
}

// Round 16
// 349.640 us; speedup vs baseline: 1.1996x; 1.0108x over previous
//
#include <hip/hip_runtime.h>
#include <math.h>

// Problem constants
#define NSEQ 8192          // B*N
#define PATCHL 16
#define HIDN 256
#define VOCABN 256

typedef __attribute__((ext_vector_type(4))) float f32x4;
typedef __attribute__((ext_vector_type(8))) short bf16x8;   // 8 bf16 = 4 VGPRs

__device__ __forceinline__ unsigned short f2bf(float f) {
    unsigned int x = __float_as_uint(f);
    unsigned int r = (x + 0x7fffu + ((x >> 16) & 1u)) >> 16;
    return (unsigned short)r;
}
__device__ __forceinline__ float bf2f(unsigned short b) {
    return __uint_as_float(((unsigned int)b) << 16);
}
__device__ __forceinline__ float sigf(float x)   { return 1.f / (1.f + __expf(-x)); }
__device__ __forceinline__ float tanhf_(float x) { return 2.f / (1.f + __expf(-2.f * x)) - 1.f; }

// ---------------------------------------------------------------------------
// Fragment-order bf16 pack of a weight matrix slice (MFMA B operand).
// ---------------------------------------------------------------------------
__global__ __launch_bounds__(256)
void pack_frag(const float* __restrict__ src, int ld, int col0, int nks,
               unsigned short* __restrict__ dst)
{
    const int g = blockIdx.x * 256 + threadIdx.x;
    const int lane = g & 63;
    const int ks = (g / 64) % nks;
    const int T  = g / (64 * nks);
    const float* s = src + (size_t)(T * 16 + (lane & 15)) * ld + col0 + ks * 32 + ((lane >> 4) & 3) * 8;
    unsigned int q[4];
#pragma unroll
    for (int j = 0; j < 4; j++) {
        unsigned int lo = f2bf(s[2 * j]);
        unsigned int hi = f2bf(s[2 * j + 1]);
        q[j] = lo | (hi << 16);
    }
    uint4 v; v.x = q[0]; v.y = q[1]; v.z = q[2]; v.w = q[3];
    *(uint4*)(dst + (size_t)g * 8) = v;
}

// ---------------------------------------------------------------------------
// bf16 MFMA GEMM: C[m][n] = sum_k A[m][k] * W[n][k] (+bias[n])
// BM=128 BN=64 BK=64, 512 threads (8 waves). Verified rounds 3-15.
// OUT_MODE: 0 = f32 row-major, 1 = bf16 row-major, 2 = bf16 gate4 interleave.
// ---------------------------------------------------------------------------
template<bool ASRC_BF16, int OUT_MODE>
__global__ __launch_bounds__(512)
void gemm_mfma(const void* __restrict__ Asrc, int lda,
               const unsigned short* __restrict__ bpack, int nks_total,
               const float* __restrict__ bias, void* __restrict__ Cdst, int ldc,
               int K)
{
    const int tid = threadIdx.x;
    const int w = tid >> 6, lane = tid & 63;
    const int l15 = lane & 15, kg = (lane >> 4) & 3;
    const int bm = blockIdx.x * 128, bn = blockIdx.y * 64;

    __shared__ unsigned short As[2][128 * 64];

    const int srow = tid >> 2;           // 0..127
    const int scol = (tid & 3) * 16;     // 0,16,32,48
    const int nkt = K / 64;

    f32x4 acc[4];
#pragma unroll
    for (int nt = 0; nt < 4; nt++) acc[nt] = 0.f;

    const int wb0 = srow * 128 + ((scol * 2) ^ ((srow & 7) << 4));
    const int wb1 = srow * 128 + ((scol * 2 + 16) ^ ((srow & 7) << 4));

#define STAGE(kt, buf) do {                                                         \
        const int gk = (kt) * 64 + scol;                                            \
        unsigned short tmp[16];                                                     \
        if (ASRC_BF16) {                                                            \
            const unsigned short* A = (const unsigned short*)Asrc;                  \
            *(uint4*)(tmp)     = *(const uint4*)(A + (size_t)(bm + srow) * lda + gk);      \
            *(uint4*)(tmp + 8) = *(const uint4*)(A + (size_t)(bm + srow) * lda + gk + 8);  \
        } else {                                                                    \
            const float* A = (const float*)Asrc;                                    \
            const float4 a0 = *(const float4*)(A + (size_t)(bm + srow) * lda + gk);       \
            const float4 a1 = *(const float4*)(A + (size_t)(bm + srow) * lda + gk + 4);   \
            const float4 a2 = *(const float4*)(A + (size_t)(bm + srow) * lda + gk + 8);   \
            const float4 a3 = *(const float4*)(A + (size_t)(bm + srow) * lda + gk + 12);  \
            tmp[0] = f2bf(a0.x);  tmp[1] = f2bf(a0.y);  tmp[2] = f2bf(a0.z);  tmp[3] = f2bf(a0.w);   \
            tmp[4] = f2bf(a1.x);  tmp[5] = f2bf(a1.y);  tmp[6] = f2bf(a1.z);  tmp[7] = f2bf(a1.w);   \
            tmp[8] = f2bf(a2.x);  tmp[9] = f2bf(a2.y);  tmp[10] = f2bf(a2.z); tmp[11] = f2bf(a2.w);  \
            tmp[12] = f2bf(a3.x); tmp[13] = f2bf(a3.y); tmp[14] = f2bf(a3.z); tmp[15] = f2bf(a3.w);  \
        }                                                                           \
        *(uint4*)((char*)As[buf] + wb0) = *(uint4*)tmp;                             \
        *(uint4*)((char*)As[buf] + wb1) = *(uint4*)(tmp + 8);                       \
    } while (0)

    STAGE(0, 0);
    __syncthreads();

    for (int kt = 0; kt < nkt; ++kt) {
        if (kt + 1 < nkt) STAGE(kt + 1, (kt + 1) & 1);
        const unsigned short* buf = As[kt & 1];
        const int row = w * 16 + l15;
#pragma unroll
        for (int ks = 0; ks < 2; ++ks) {
            const int bo = row * 128 + (((ks * 64) + kg * 16) ^ ((row & 7) << 4));
            const bf16x8 a = *(const bf16x8*)((const char*)buf + bo);
#pragma unroll
            for (int nt = 0; nt < 4; ++nt) {
                const int T = blockIdx.y * 4 + nt;
                const bf16x8 b = *(const bf16x8*)(bpack + (((size_t)T * nks_total + (kt * 2 + ks)) * 64 + lane) * 8);
                acc[nt] = __builtin_amdgcn_mfma_f32_16x16x32_bf16(a, b, acc[nt], 0, 0, 0);
            }
        }
        __syncthreads();
    }
#undef STAGE

#pragma unroll
    for (int nt = 0; nt < 4; ++nt) {
        const int n = bn + nt * 16 + l15;
        const float bv = bias ? bias[n] : 0.f;
#pragma unroll
        for (int rr = 0; rr < 4; ++rr) {
            const int m = bm + w * 16 + kg * 4 + rr;
            const float v = acc[nt][rr] + bv;
            if (OUT_MODE == 0)      ((float*)Cdst)[(size_t)m * ldc + n] = v;
            else if (OUT_MODE == 1) ((unsigned short*)Cdst)[(size_t)m * ldc + n] = f2bf(v);
            else                    ((unsigned short*)Cdst)[(size_t)m * 1024 + (n & 255) * 4 + (n >> 8)] = f2bf(v);
        }
    }
}

// ---------------------------------------------------------------------------
// Fused GRU scan, 32 seqs/block, 512 threads (8 waves), 256 blocks (1/CU),
// GATE-SEQUENTIAL accumulation. Insight: the MFMA C-layout maps each
// thread's acc element (mt,nt,rr) to exactly the gate-set (sl,u) that the
// SAME thread applies -> gates r,z,n can be computed one-at-a-time with
// the nonlinearity applied immediately (accr -> r, freed; accz -> z,
// freed; accn held to the barrier). Peak live regs ~111 < the hard 128
// cap, so the 32-seq shape (which halves the 384 KB/step wpack stream
// cost per seq vs r11's 16-seq blocks) no longer spills. premix is a
// per-thread L2 ushort4 gather (128-B segments, 512 KB table L2-resident)
// -> no barrier dependency, so r/z apply before the single H barrier.
// LDS: LG 66 KB + H 16 KB + BYs 2 KB = 84 KB.
// ---------------------------------------------------------------------------
#define G4S 1032   // gate4 row stride in shorts (1024 + 8 pad)
__global__ __launch_bounds__(512)
void gru_scan_fused(const int* __restrict__ bytes,          // [NSEQ*16]
                    const unsigned short* __restrict__ latg4,   // [NSEQ][1024] gate4 bf16 (incl b_ih)
                    const unsigned short* __restrict__ pmx4,    // [256][1024] gate4 bf16
                    const unsigned short* __restrict__ wpack,   // 48 gate tiles
                    const float* __restrict__ b_hh,         // [768]
                    unsigned short* __restrict__ hh,        // [SPC*16][256] bf16
                    int seq0)
{
    const int tid  = threadIdx.x;
    const int w    = tid >> 6;
    const int lane = tid & 63;
    const int l15  = lane & 15;
    const int kg   = (lane >> 4) & 3;
    const int s0l  = blockIdx.x * 32;            // chunk-local
    const int s0g  = seq0 + s0l;                 // global

    __shared__ unsigned short LG[32 * G4S];      // 66 KB
    __shared__ unsigned short H[32 * 256];       // 16 KB
    __shared__ int BYs[512];                     // 2 KB

    BYs[tid] = bytes[(size_t)s0g * PATCHL + tid];

    // latg (step-invariant) -> LDS once, coalesced uint4 loads
#pragma unroll
    for (int j = 0; j < 8; ++j) {
        const int idx = j * 512 + tid;           // uint4 index; 128 per row
        const int row = idx >> 7, col = idx & 127;
        *(uint4*)(LG + row * G4S + col * 8) =
            *(const uint4*)(latg4 + (size_t)(s0g + row) * 1024 + col * 8);
    }

    float bhr[2], bhz[2], bhn[2];
#pragma unroll
    for (int nt = 0; nt < 2; nt++) {
        const int u = w * 32 + nt * 16 + l15;
        bhr[nt] = b_hh[u]; bhz[nt] = b_hh[256 + u]; bhn[nt] = b_hh[512 + u];
    }

    float hreg[2][2][4];                         // h for (mt,nt,rr)
#pragma unroll
    for (int mt = 0; mt < 2; mt++)
#pragma unroll
        for (int nt = 0; nt < 2; nt++)
#pragma unroll
            for (int rr = 0; rr < 4; rr++) hreg[mt][nt][rr] = 0.f;

    __syncthreads();    // BYs + LG ready

    // one gate's MFMA accumulation (reads H + wpack stream)
#define MFMA_GATE(gg, acc) do {                                                     \
        _Pragma("unroll")                                                           \
        for (int ks = 0; ks < 8; ks += 2) {                                         \
            bf16x8 B[2][2];                                                         \
            _Pragma("unroll")                                                       \
            for (int dk = 0; dk < 2; ++dk)                                          \
                _Pragma("unroll")                                                   \
                for (int nt = 0; nt < 2; ++nt) {                                    \
                    const int T = (gg) * 16 + w * 2 + nt;                           \
                    B[dk][nt] = *(const bf16x8*)(wpack + (((size_t)T * 8 + ks + dk) * 64 + lane) * 8); \
                }                                                                   \
            _Pragma("unroll")                                                       \
            for (int dk = 0; dk < 2; ++dk)                                          \
                _Pragma("unroll")                                                   \
                for (int mt = 0; mt < 2; ++mt) {                                    \
                    const int s = mt * 16 + l15;                                    \
                    const int off = ((ks + dk) * 64 + kg * 16) ^ ((l15 & 7) << 4);  \
                    const bf16x8 a = *(const bf16x8*)(H + s * 256 + (off >> 1));    \
                    _Pragma("unroll")                                               \
                    for (int nt = 0; nt < 2; ++nt)                                  \
                        acc[mt][nt] = __builtin_amdgcn_mfma_f32_16x16x32_bf16(a, B[dk][nt], acc[mt][nt], 0, 0, 0); \
                }                                                                   \
        }                                                                           \
    } while (0)

    for (int p = 0; p < PATCHL; ++p) {
        // ---- 0. per-thread premix gather (L2, issued early) ----
        ushort4 pmreg[2][2][4];
#pragma unroll
        for (int mt = 0; mt < 2; mt++)
#pragma unroll
            for (int nt = 0; nt < 2; nt++) {
                const int u = w * 32 + nt * 16 + l15;
#pragma unroll
                for (int rr = 0; rr < 4; rr++) {
                    const int sl = mt * 16 + kg * 4 + rr;
                    const int bv = p ? BYs[sl * PATCHL + p - 1] : 0;
                    pmreg[mt][nt][rr] = *(const ushort4*)(pmx4 + (size_t)bv * 1024 + u * 4);
                }
            }

        // ---- 1. coalesced hh write of h(p-1) (reads H, pre-overwrite) ----
        if (p) {
#pragma unroll
            for (int rj = 0; rj < 4; ++rj) {
                const int row = w * 4 + rj;
                const int boff = (lane * 8) ^ ((row & 7) << 4);   // un-swizzle
                const ushort4 v = *(const ushort4*)((const char*)(H + row * 256) + boff);
                *(ushort4*)(hh + ((size_t)(s0l + row) * PATCHL + (p - 1)) * 256 + lane * 4) = v;
            }
        }

        // ---- 2. gate r: MFMA then immediate apply (frees accr) ----
        f32x4 acc[2][2];
#pragma unroll
        for (int mt = 0; mt < 2; mt++)
#pragma unroll
            for (int nt = 0; nt < 2; nt++) acc[mt][nt] = 0.f;
        if (p) MFMA_GATE(0, acc);

        float rv[2][2][4], xz[2][2][4], xn[2][2][4];
#pragma unroll
        for (int mt = 0; mt < 2; mt++)
#pragma unroll
            for (int nt = 0; nt < 2; nt++) {
                const int u = w * 32 + nt * 16 + l15;
#pragma unroll
                for (int rr = 0; rr < 4; rr++) {
                    const int sl = mt * 16 + kg * 4 + rr;
                    const ushort4 lg4 = *(const ushort4*)(LG + sl * G4S + u * 4);
                    const ushort4 pm4 = pmreg[mt][nt][rr];
                    const float xr = bf2f(lg4.x) + bf2f(pm4.x) + bhr[nt];
                    rv[mt][nt][rr] = sigf(xr + acc[mt][nt][rr]);
                    xz[mt][nt][rr] = bf2f(lg4.y) + bf2f(pm4.y) + bhz[nt];
                    xn[mt][nt][rr] = bf2f(lg4.z) + bf2f(pm4.z);
                }
            }

        // ---- 3. gate z: MFMA then immediate apply (frees accz, xz) ----
#pragma unroll
        for (int mt = 0; mt < 2; mt++)
#pragma unroll
            for (int nt = 0; nt < 2; nt++) acc[mt][nt] = 0.f;
        if (p) MFMA_GATE(1, acc);

        float zv[2][2][4];
#pragma unroll
        for (int mt = 0; mt < 2; mt++)
#pragma unroll
            for (int nt = 0; nt < 2; nt++)
#pragma unroll
                for (int rr = 0; rr < 4; rr++)
                    zv[mt][nt][rr] = sigf(xz[mt][nt][rr] + acc[mt][nt][rr]);

        // ---- 4. gate n: MFMA (acc held across the barrier) ----
#pragma unroll
        for (int mt = 0; mt < 2; mt++)
#pragma unroll
            for (int nt = 0; nt < 2; nt++) acc[mt][nt] = 0.f;
        if (p) MFMA_GATE(2, acc);

        __syncthreads();   // all H reads (copy + 3 gate MFMAs) complete

        // ---- 5. n + state update; write h(p) into H ----
#pragma unroll
        for (int mt = 0; mt < 2; mt++)
#pragma unroll
            for (int nt = 0; nt < 2; nt++) {
                const int u = w * 32 + nt * 16 + l15;
#pragma unroll
                for (int rr = 0; rr < 4; rr++) {
                    const int sl = mt * 16 + kg * 4 + rr;
                    const float n = tanhf_(xn[mt][nt][rr] + rv[mt][nt][rr] * (acc[mt][nt][rr] + bhn[nt]));
                    const float hn_ = (1.f - zv[mt][nt][rr]) * n + zv[mt][nt][rr] * hreg[mt][nt][rr];
                    hreg[mt][nt][rr] = hn_;
                    const int bo = (2 * u) ^ ((sl & 7) << 4);
                    H[sl * 256 + (bo >> 1)] = f2bf(hn_);
                }
            }
        __syncthreads();   // h(p) visible
    }
#undef MFMA_GATE

    // ---- final hh write for p = 15 ----
#pragma unroll
    for (int rj = 0; rj < 4; ++rj) {
        const int row = w * 4 + rj;
        const int boff = (lane * 8) ^ ((row & 7) << 4);
        const ushort4 v = *(const ushort4*)((const char*)(H + row * 256) + boff);
        *(ushort4*)(hh + ((size_t)(s0l + row) * PATCHL + (PATCHL - 1)) * 256 + lane * 4) = v;
    }
}

// ---------------------------------------------------------------------------
extern "C" void kernel_launch(void* const* d_in, const int* in_sizes, int n_in,
                              void* d_out, int out_size, void* d_ws, size_t ws_size,
                              hipStream_t stream)
{
    const float* latents = (const float*)d_in[0];   // [8192][1024]
    const int*   tb      = (const int*)d_in[1];     // [8192*16]
    const float* W_proj  = (const float*)d_in[2];   // [256][1024]
    const float* b_proj  = (const float*)d_in[3];   // [256]
    const float* emb     = (const float*)d_in[4];   // [256][256]
    const float* W_ih    = (const float*)d_in[5];   // [768][512]
    const float* W_hh    = (const float*)d_in[6];   // [768][256]
    const float* b_ih    = (const float*)d_in[7];   // [768]
    const float* b_hh    = (const float*)d_in[8];   // [768]
    const float* W_head  = (const float*)d_in[9];   // [256][256]
    const float* b_head  = (const float*)d_in[10];  // [256]
    float* out = (float*)d_out;

    // ---- workspace layout (bytes) ----
    char* w = (char*)d_ws;
    unsigned short* latg4   = (unsigned short*)w;          w += (size_t)NSEQ * 1024 * 2;    // 16.8 MB
    unsigned short* ctxb    = (unsigned short*)w;          w += (size_t)NSEQ * HIDN * 2;    // 4.2 MB
    unsigned short* pmx4    = (unsigned short*)w;          w += 256 * 1024 * 2;             // 512 KB
    unsigned short* bpack1  = (unsigned short*)w;          w += 16 * 32 * 64 * 8 * 2;
    unsigned short* bpack2  = (unsigned short*)w;          w += 48 * 8 * 64 * 8 * 2;
    unsigned short* bpack3  = (unsigned short*)w;          w += 48 * 8 * 64 * 8 * 2;
    unsigned short* wpackG  = (unsigned short*)w;          w += 48 * 8 * 64 * 8 * 2;        // gates
    unsigned short* bpackH  = (unsigned short*)w;          w += 16 * 8 * 64 * 8 * 2;        // head
    unsigned short* hh_c    = (unsigned short*)w;
    const size_t fixed_bytes = (size_t)(w - (char*)d_ws);
    const size_t chunk_full  = (size_t)NSEQ * PATCHL * 256 * 2;          // hh = 67 MB

    int nch = 1;
    while (nch < 16 && fixed_bytes + chunk_full / nch > ws_size) nch <<= 1;
    const int SPC = NSEQ / nch;                    // seqs per chunk

    // ---- weight packs (fragment-ordered bf16) ----
    hipLaunchKernelGGL(pack_frag, dim3(128), dim3(256), 0, stream, W_proj, 1024, 0, 32, bpack1);
    hipLaunchKernelGGL(pack_frag, dim3(96),  dim3(256), 0, stream, W_ih,   512, 256, 8, bpack2);
    hipLaunchKernelGGL(pack_frag, dim3(96),  dim3(256), 0, stream, W_ih,   512, 0,   8, bpack3);
    hipLaunchKernelGGL(pack_frag, dim3(96),  dim3(256), 0, stream, W_hh,   256, 0,   8, wpackG);
    hipLaunchKernelGGL(pack_frag, dim3(32),  dim3(256), 0, stream, W_head, 256, 0,   8, bpackH);

    // pmx4(gate4 bf16) = emb @ W_ih[:,0:256]^T     [256][1024]
    hipLaunchKernelGGL((gemm_mfma<false, 2>), dim3(2, 12), dim3(512), 0, stream,
                       emb, 256, bpack3, 8, nullptr, pmx4, 1024, 256);
    // ctx(bf16) = latents @ W_proj^T + b_proj      [8192][256]
    hipLaunchKernelGGL((gemm_mfma<false, 1>), dim3(NSEQ / 128, 4), dim3(512), 0, stream,
                       latents, 1024, bpack1, 32, b_proj, ctxb, 256, 1024);
    // latg4(gate4 bf16) = ctx @ W_ih[:,256:512]^T + b_ih   [8192][1024]
    hipLaunchKernelGGL((gemm_mfma<true, 2>), dim3(NSEQ / 128, 12), dim3(512), 0, stream,
                       ctxb, 256, bpack2, 8, b_ih, latg4, 1024, 256);

    // ---- per-chunk: fused scan -> head GEMM (stream-ordered) ----
    for (int c = 0; c < nch; ++c) {
        const int seq0 = c * SPC;
        hipLaunchKernelGGL(gru_scan_fused, dim3(SPC / 32), dim3(512), 0, stream,
                           tb, latg4, pmx4, wpackG, b_hh, hh_c, seq0);
        // logits = h_hist @ W_head^T + b_head    [SPC*16][256]
        hipLaunchKernelGGL((gemm_mfma<true, 0>), dim3(SPC * PATCHL / 128, 4), dim3(512), 0, stream,
                           hh_c, 256, bpackH, 8, b_head,
                           out + (size_t)seq0 * PATCHL * VOCABN, 256, 256);
    }
}